// Round 11
// baseline (465.527 us; speedup 1.0000x reference)
//
#include <hip/hip_runtime.h>
#include <hip/hip_fp16.h>
#include <math.h>

// DiagonalLSTM: B=8, Cin=HID=128, H=64, W=64, K=2, T = 2W-1 = 127 steps.
//
// Round 11 design (round 10 + fused prologue):
//   - TWO dispatches total. #1 prep_all: weight fragments + hx sentinel fill
//     + zph sentinel fill (f16 NaN 0x7E00 -- unreachable from packing finite
//     values; mandatory because ws poison 0xAA is a *valid* f16 pattern).
//   - #2 lstm_fused, 288 blocks x 512 thr: blocks 0..31 = persistent lstm
//     (round-10 structure: sentinel hx exchange, 1 barrier/step, reg-buffered
//     out); blocks 32..287 = zpre (2 (b,r) positions/block, 256-thr halves).
//     zph crosses XCDs within one kernel -> producer uses relaxed agent
//     atomic 8B stores, consumer uses relaxed agent atomic 8B loads
//     (1-step-prefetched) + per-wave ballot-spin validation before gates.
//     Deadlock-free: zpre blocks are finite & independent; lstm blocks wait
//     only on zpre data + upstream row-groups.

#define HID 128
#define BB 8
#define HH 64
#define WW 64
#define TT 127

typedef _Float16 v8h __attribute__((ext_vector_type(8)));
typedef float v4f __attribute__((ext_vector_type(4)));

#define SENT64 0x7E007E007E007E00ULL  // 4x f16 NaN

__device__ __forceinline__ float fsig(float x) {
  x = __builtin_fmaxf(__builtin_fminf(x, 30.f), -30.f);
  float e = __builtin_amdgcn_exp2f(x * -1.44269504f);
  return __builtin_amdgcn_rcpf(1.f + e);
}
__device__ __forceinline__ float ftanh_(float x) {
  x = __builtin_fmaxf(__builtin_fminf(x, 15.f), -15.f);
  float e = __builtin_amdgcn_exp2f(x * 2.88539009f);
  return (e - 1.f) * __builtin_amdgcn_rcpf(e + 1.f);
}

// ---- prep_all: w frags + hx sentinel + zph sentinel ----
__global__ __launch_bounds__(256) void prep_all(
    const float* __restrict__ w_ss, const float* __restrict__ w_is,
    _Float16* __restrict__ wp, _Float16* __restrict__ wisa,
    unsigned long long* __restrict__ hx, __half* __restrict__ zph) {
  int idx = blockIdx.x * 256 + threadIdx.x;
  if (idx < 131072) {
    // w_ss -> Wcat(512x256) A-frags: wp[(((mt*8+kt)*64+L)*8+j)]
    int j = idx & 7;
    int L = (idx >> 3) & 63;
    int kt = (idx >> 9) & 7;
    int mt = idx >> 12;  // 0..31
    int O = mt * 16 + (L & 15);
    int k = kt * 32 + ((L >> 4) & 3) * 8 + j;
    float v = (k < 128) ? w_ss[(size_t)O * 256 + k * 2]
                        : w_ss[(size_t)O * 256 + (k - 128) * 2 + 1];
    wp[idx] = (_Float16)v;
  } else if (idx < 196608) {
    // w_is (512x128) A-frags: wisa[(((mt*4+kt)*64+L)*8+j)]
    int i2 = idx - 131072;
    int j = i2 & 7;
    int L = (i2 >> 3) & 63;
    int kt = (i2 >> 9) & 3;
    int mt = i2 >> 11;  // 0..31
    int O = mt * 16 + (L & 15);
    int k = kt * 32 + ((L >> 4) & 3) * 8 + j;
    wisa[i2] = (_Float16)w_is[(size_t)O * 128 + k];
  } else if (idx < 456704) {
    hx[idx - 196608] = SENT64;  // [TT][8][4][64] boundary sentinel
  } else if (idx < 456704 + 2097152) {
    // zph sentinel fill: 16.7M halfs = 2,097,152 uint4
    uint4 s;
    s.x = 0x7E007E00u;
    s.y = 0x7E007E00u;
    s.z = 0x7E007E00u;
    s.w = 0x7E007E00u;
    ((uint4*)zph)[idx - 456704] = s;
  }
}

// ---------------- fused kernel ----------------
#define HROW 136  // padded LDS row stride in halfs

__global__ __launch_bounds__(512, 2) void lstm_fused(
    const float* __restrict__ x, const _Float16* __restrict__ wisa,
    __half* __restrict__ zph, const _Float16* __restrict__ wp,
    const float* __restrict__ b_is, const float* __restrict__ b_ss,
    unsigned long long* __restrict__ hx,  // [TT][8][4][64], sentinel-filled
    float* __restrict__ out) {
  const int blk = blockIdx.x;
  const int tid = threadIdx.x;
  // shared pool: zpre needs 2*64*136 halfs (34816B); lstm uses first 9792B
  __shared__ __align__(16) _Float16 smem[2 * 64 * HROW];

  if (blk >= 32) {
    // ================= zpre role: 2 positions per block =================
    const int half = tid >> 8;   // 0,1
    const int t2 = tid & 255;
    const int posi = (blk - 32) * 2 + half;  // 0..511
    const int b = posi >> 6;
    const int r = posi & 63;
    _Float16* xt = smem + half * (64 * HROW);  // [w][c]

    // stage x(b,:,r,:) -> xt transposed (f32 -> f16)
    {
      int c = t2 >> 1;
      int wh = (t2 & 1) * 32;
      const float4* xs =
          (const float4*)&x[(((size_t)b * 128 + c) * HH + r) * WW + wh];
#pragma unroll
      for (int i = 0; i < 8; i++) {
        float4 v = xs[i];
        xt[(wh + 4 * i + 0) * HROW + c] = (_Float16)v.x;
        xt[(wh + 4 * i + 1) * HROW + c] = (_Float16)v.y;
        xt[(wh + 4 * i + 2) * HROW + c] = (_Float16)v.z;
        xt[(wh + 4 * i + 3) * HROW + c] = (_Float16)v.w;
      }
    }
    __syncthreads();

    const int L = t2 & 63;
    const int wv2 = t2 >> 6;  // 0..3
    const int quad = L >> 4;
    const int l15 = L & 15;
    const int wcol = wv2 * 16 + l15;
    v8h bf[4];
#pragma unroll
    for (int kt = 0; kt < 4; kt++)
      bf[kt] = *(const v8h*)&xt[wcol * HROW + kt * 32 + quad * 8];

    const size_t pos = ((size_t)b * HH + r) * WW + wcol;
    unsigned long long* zp64 = (unsigned long long*)zph;
    const v8h* wa8 = (const v8h*)wisa;

#pragma unroll 4
    for (int mt = 0; mt < 32; mt++) {
      v4f acc = (v4f){0.f, 0.f, 0.f, 0.f};
#pragma unroll
      for (int kt = 0; kt < 4; kt++) {
        v8h af = wa8[((size_t)mt * 4 + kt) * 64 + L];
        acc = __builtin_amdgcn_mfma_f32_16x16x32_f16(af, bf[kt], acc, 0, 0, 0);
      }
      __half2 lo = __floats2half2_rn(acc[0], acc[1]);
      __half2 hi = __floats2half2_rn(acc[2], acc[3]);
      unsigned long long pk =
          ((unsigned long long)*(unsigned*)&hi << 32) | *(unsigned*)&lo;
      // u64 index: pos*128 + ((mt&7)*4+quad)*4 + (mt>>3)
      __hip_atomic_store(&zp64[pos * 128 + ((mt & 7) * 4 + quad) * 4 + (mt >> 3)],
                         pk, __ATOMIC_RELAXED, __HIP_MEMORY_SCOPE_AGENT);
    }
    return;
  }

  // ================= lstm role (blocks 0..31) =================
  const int rgr = blk >> 2;  // row group 0..7
  const int bg = blk & 3;    // batch group 0..3
  const int R0 = rgr * 8;
  const int wv = tid >> 6;  // wave 0..7
  const int L = tid & 63;
  const int quad = L >> 4;
  const int l15 = L & 15;
  const int rl = l15 >> 1;
  const int bl = l15 & 1;
  const int b = bg * 2 + bl;
  const int r = R0 + rl;
  const int uq0 = 16 * wv + quad * 4;

  _Float16* h_lds0 = smem;                    // buffer 0: 9*2*HROW halfs
  _Float16* h_lds1 = smem + 9 * 2 * HROW;     // buffer 1
  for (int i = tid; i < (2 * 9 * 2 * HROW) / 2; i += 512)
    ((unsigned*)smem)[i] = 0u;

  v8h wfrag[4][8];
  {
    const v8h* wp8 = (const v8h*)wp;
#pragma unroll
    for (int g = 0; g < 4; g++)
#pragma unroll
      for (int kt = 0; kt < 8; kt++)
        wfrag[g][kt] = wp8[((size_t)((8 * g + wv) * 8 + kt)) * 64 + L];
  }

  float bsum[4][4];
#pragma unroll
  for (int g = 0; g < 4; g++)
#pragma unroll
    for (int rg2 = 0; rg2 < 4; rg2++) {
      int O = g * 128 + uq0 + rg2;
      bsum[g][rg2] = b_is[O] + b_ss[O];
    }

  float c[4] = {0.f, 0.f, 0.f, 0.f};
  float4 outb[4];
#pragma unroll
  for (int i = 0; i < 4; i++) outb[i] = make_float4(0.f, 0.f, 0.f, 0.f);

  const int ebl = L >> 5;
  const int eu = (L & 31) * 4;
  const int exp_idx = bl * 32 + 4 * wv + quad;
  const bool is_cons = (wv == 0) && (rgr > 0);
  const unsigned long long* zph64 = (const unsigned long long*)zph;
  const int zgi = (4 * wv + quad) * 4;  // u64 group base within pos

  // ---- zp for t=0 ----
  union ZU {
    unsigned long long q[4];
    __half h[16];  // h[g*4 + rg2]
  } zu;
#pragma unroll
  for (int g = 0; g < 4; g++) zu.q[g] = 0ull;
  if (r == 0) {
    size_t zi = (size_t)b * HH * WW * 128 + zgi;
#pragma unroll
    for (int g = 0; g < 4; g++)
      zu.q[g] = __hip_atomic_load(&zph64[zi + g], __ATOMIC_RELAXED,
                                  __HIP_MEMORY_SCOPE_AGENT);
  }

  unsigned long long pend = 0ull;
  if (is_cons) {
    pend = __hip_atomic_load(&hx[(((size_t)0 * 8 + (rgr - 1)) * 4 + bg) * 64 + L],
                             __ATOMIC_RELAXED, __HIP_MEMORY_SCOPE_AGENT);
  }

  __syncthreads();

  for (int t = 0; t < TT; t++) {
    _Float16* rbuf = (t & 1) ? h_lds1 : h_lds0;
    _Float16* wbuf = (t & 1) ? h_lds0 : h_lds1;

    // ---- issue next boundary load (hx[t+1], consumed end of t+1) ----
    unsigned long long newp = 0ull;
    if (is_cons && (t + 1) < TT) {
      newp = __hip_atomic_load(
          &hx[(((size_t)(t + 1) * 8 + (rgr - 1)) * 4 + bg) * 64 + L],
          __ATOMIC_RELAXED, __HIP_MEMORY_SCOPE_AGENT);
    }

    // ---- MFMA ----
    v4f acc[4];
#pragma unroll
    for (int g = 0; g < 4; g++) acc[g] = (v4f){0.f, 0.f, 0.f, 0.f};
#pragma unroll
    for (int kt = 0; kt < 8; kt++) {
      const int slot = (kt < 4) ? rl : (rl + 1);
      v8h bfr = *(const v8h*)&rbuf[(slot * 2 + bl) * HROW +
                                   (kt & 3) * 32 + quad * 8];
#pragma unroll
      for (int g = 0; g < 4; g++)
        acc[g] = __builtin_amdgcn_mfma_f32_16x16x32_f16(wfrag[g][kt], bfr,
                                                        acc[g], 0, 0, 0);
    }

    const int w = t - r;
    const bool inband = (w >= 0) && (w < WW);

    // ---- validate zu (sentinel -> zpre not done yet; rare, early only) ----
    {
      bool bad = inband && ((zu.q[0] == SENT64) || (zu.q[1] == SENT64) ||
                            (zu.q[2] == SENT64) || (zu.q[3] == SENT64));
      while (__ballot(bad) != 0ull) {
        __builtin_amdgcn_s_sleep(1);
        if (bad) {
          size_t zi = (((size_t)b * HH + r) * WW + w) * 128 + zgi;
#pragma unroll
          for (int g = 0; g < 4; g++)
            zu.q[g] = __hip_atomic_load(&zph64[zi + g], __ATOMIC_RELAXED,
                                        __HIP_MEMORY_SCOPE_AGENT);
          bad = (zu.q[0] == SENT64) || (zu.q[1] == SENT64) ||
                (zu.q[2] == SENT64) || (zu.q[3] == SENT64);
        }
      }
    }

    // ---- gates ----
    float hv[4];
#pragma unroll
    for (int rg2 = 0; rg2 < 4; rg2++) {
      float z0 = acc[0][rg2] + bsum[0][rg2] + __half2float(zu.h[0 * 4 + rg2]);
      float z1 = acc[1][rg2] + bsum[1][rg2] + __half2float(zu.h[1 * 4 + rg2]);
      float z2 = acc[2][rg2] + bsum[2][rg2] + __half2float(zu.h[2 * 4 + rg2]);
      float z3 = acc[3][rg2] + bsum[3][rg2] + __half2float(zu.h[3 * 4 + rg2]);
      float iv = fsig(z0);
      float fv = fsig(z1);
      float ov = fsig(z2);
      float gv = ftanh_(z3);
      c[rg2] = fv * c[rg2] + iv * gv;
      hv[rg2] = ov * ftanh_(c[rg2]);
    }

    // ---- h(t) -> write buffer slots 1..8 ----
    {
      __half2 lo = __floats2half2_rn(hv[0], hv[1]);
      __half2 hi = __floats2half2_rn(hv[2], hv[3]);
      uint2 pk;
      pk.x = *(unsigned*)&lo;
      pk.y = *(unsigned*)&hi;
      *(uint2*)&wbuf[((rl + 1) * 2 + bl) * HROW + uq0] = pk;
    }

    // ---- export h(t)[R0+7]: fire-and-forget (data == flag) ----
    if (rgr < 7 && l15 >= 14) {
      __half2 lo = __floats2half2_rn(hv[0], hv[1]);
      __half2 hi = __floats2half2_rn(hv[2], hv[3]);
      unsigned long long pk =
          ((unsigned long long)*(unsigned*)&hi << 32) | *(unsigned*)&lo;
      __hip_atomic_store(&hx[(((size_t)t * 8 + rgr) * 4 + bg) * 64 + exp_idx],
                         pk, __ATOMIC_RELAXED, __HIP_MEMORY_SCOPE_AGENT);
    }

    // ---- out shift-window; 16B flush every 4 steps ----
#pragma unroll
    for (int rg2 = 0; rg2 < 4; rg2++) {
      outb[rg2].x = outb[rg2].y;
      outb[rg2].y = outb[rg2].z;
      outb[rg2].z = outb[rg2].w;
      outb[rg2].w = hv[rg2];
    }
    if (inband && (w & 3) == 3) {
      float* op_ = out + (((size_t)b * HID + uq0) * HH + r) * WW + (w - 3);
#pragma unroll
      for (int rg2 = 0; rg2 < 4; rg2++) {
        *(float4*)(op_ + (size_t)rg2 * (HH * WW)) = outb[rg2];
      }
    }

    // ---- zp prefetch for t+1 ----
    {
      const int wn = t + 1 - r;
      if (wn >= 0 && wn < WW) {
        size_t zi = (((size_t)b * HH + r) * WW + wn) * 128 + zgi;
#pragma unroll
        for (int g = 0; g < 4; g++)
          zu.q[g] = __hip_atomic_load(&zph64[zi + g], __ATOMIC_RELAXED,
                                      __HIP_MEMORY_SCOPE_AGENT);
      } else {
#pragma unroll
        for (int g = 0; g < 4; g++) zu.q[g] = 0ull;
      }
    }

    // ---- validate pend (hx[t] = h(t)[R0-1]) -> write buffer slot 0 ----
    if (is_cons) {
      const unsigned long long* addr =
          &hx[(((size_t)t * 8 + (rgr - 1)) * 4 + bg) * 64 + L];
      while (__ballot(pend == SENT64) != 0ull) {
        __builtin_amdgcn_s_sleep(1);
        pend = __hip_atomic_load(addr, __ATOMIC_RELAXED,
                                 __HIP_MEMORY_SCOPE_AGENT);
      }
      *(unsigned long long*)&wbuf[(0 * 2 + ebl) * HROW + eu] = pend;
      pend = newp;
    }

    __syncthreads();
  }
}

// ================= round-1 fallback path (proven correct) =================
__global__ __launch_bounds__(256) void transpose_x(const float* __restrict__ x,
                                                   float* __restrict__ xT) {
  int b = blockIdx.x >> 6;
  int r = blockIdx.x & 63;
  __shared__ float tile[32][65];
  for (int cc = 0; cc < 4; cc++) {
    int cl = threadIdx.x >> 6;
    int w = threadIdx.x & 63;
#pragma unroll
    for (int k = 0; k < 8; k++) {
      int c_loc = k * 4 + cl;
      int c = cc * 32 + c_loc;
      tile[c_loc][w] = x[(((size_t)b * 128 + c) * HH + r) * WW + w];
    }
    __syncthreads();
    int cs = threadIdx.x & 31;
    int wp = threadIdx.x >> 5;
#pragma unroll
    for (int k = 0; k < 8; k++) {
      int w2 = wp * 8 + k;
      xT[(((size_t)b * HH + r) * WW + w2) * 128 + cc * 32 + cs] = tile[cs][w2];
    }
    __syncthreads();
  }
}

__global__ __launch_bounds__(256) void step_kernel(
    const float* __restrict__ x, const float* __restrict__ xT, int use_xT,
    const float* __restrict__ w_is, const float* __restrict__ b_is,
    const float* __restrict__ w_ss, const float* __restrict__ b_ss,
    const float* __restrict__ h_prev, float* __restrict__ h_next,
    float* __restrict__ c_state, float* __restrict__ out, int t) {
  const int rg = blockIdx.x;
  const int q = blockIdx.y;
  const int r0 = rg * 2;
  const int tid = threadIdx.x;
  const int o_loc = tid & 63;
  const int k4 = tid >> 6;
  const int g_ = o_loc >> 4;
  const int u_ = o_loc & 15;
  const int O = g_ * 128 + q * 16 + u_;
  const int i0 = k4 * 32;

  __shared__ __align__(16) float h_in[3][BB][HID];
  __shared__ float zred[16][4][65];

  for (int idx = tid; idx < 3 * BB * HID; idx += 256) {
    int row_sel = idx >> 10;
    int rem = idx & 1023;
    int b = rem >> 7;
    int u = rem & 127;
    int rr = r0 - 1 + row_sel;
    h_in[row_sel][b][u] = (rr >= 0) ? h_prev[((size_t)b * HH + rr) * HID + u] : 0.0f;
  }

  float wr0[32], wr1[32], wz[32];
  {
    const float4* wss4 = (const float4*)(w_ss + ((size_t)O * 128 + i0) * 2);
#pragma unroll
    for (int j = 0; j < 16; j++) {
      float4 v = wss4[j];
      wr0[2 * j] = v.x;
      wr1[2 * j] = v.y;
      wr0[2 * j + 1] = v.z;
      wr1[2 * j + 1] = v.w;
    }
    const float4* wis4 = (const float4*)(w_is + (size_t)O * 128 + i0);
#pragma unroll
    for (int j = 0; j < 8; j++) {
      float4 v = wis4[j];
      wz[4 * j] = v.x;
      wz[4 * j + 1] = v.y;
      wz[4 * j + 2] = v.z;
      wz[4 * j + 3] = v.w;
    }
  }

  __syncthreads();

  float acc[2][BB];
#pragma unroll
  for (int rl = 0; rl < 2; rl++)
#pragma unroll
    for (int b = 0; b < BB; b++) acc[rl][b] = 0.0f;

#pragma unroll
  for (int jb = 0; jb < 8; jb++) {
    int ib = i0 + jb * 4;
#pragma unroll
    for (int b = 0; b < BB; b++) {
      const float4 hm4 = *(const float4*)&h_in[0][b][ib];
      const float4 hc4 = *(const float4*)&h_in[1][b][ib];
      const float4 hp4 = *(const float4*)&h_in[2][b][ib];
      const float* hm = (const float*)&hm4;
      const float* hc = (const float*)&hc4;
      const float* hq = (const float*)&hp4;
#pragma unroll
      for (int jj = 0; jj < 4; jj++) {
        float w0v = wr0[jb * 4 + jj];
        float w1v = wr1[jb * 4 + jj];
        acc[0][b] += w0v * hm[jj] + w1v * hc[jj];
        acc[1][b] += w0v * hc[jj] + w1v * hq[jj];
      }
    }
  }

#pragma unroll
  for (int rl = 0; rl < 2; rl++) {
    int rr = r0 + rl;
    int wcol = t - rr;
    if (wcol >= 0 && wcol < WW) {
      if (use_xT) {
        for (int b = 0; b < BB; b++) {
          const float4* xp =
              (const float4*)(xT + (((size_t)b * HH + rr) * WW + wcol) * 128 + i0);
#pragma unroll
          for (int j = 0; j < 8; j++) {
            float4 v = xp[j];
            acc[rl][b] += wz[4 * j] * v.x + wz[4 * j + 1] * v.y +
                          wz[4 * j + 2] * v.z + wz[4 * j + 3] * v.w;
          }
        }
      } else {
        for (int b = 0; b < BB; b++) {
          const float* xb = x + (((size_t)b * 128 + i0) * HH + rr) * WW + wcol;
#pragma unroll
          for (int j = 0; j < 32; j++) {
            acc[rl][b] += wz[j] * xb[(size_t)j * HH * WW];
          }
        }
      }
    }
  }

#pragma unroll
  for (int rl = 0; rl < 2; rl++)
#pragma unroll
    for (int b = 0; b < BB; b++) zred[rl * 8 + b][k4][o_loc] = acc[rl][b];
  __syncthreads();

  {
    int u = tid >> 4;
    int cell = tid & 15;
    int rl = cell >> 3;
    int b = cell & 7;
    int rr = r0 + rl;
    float z[4];
#pragma unroll
    for (int gg = 0; gg < 4; gg++) {
      int ol = gg * 16 + u;
      float s = zred[cell][0][ol] + zred[cell][1][ol] + zred[cell][2][ol] +
                zred[cell][3][ol];
      int Og = gg * 128 + q * 16 + u;
      z[gg] = s + b_is[Og] + b_ss[Og];
    }
    float iv = 1.0f / (1.0f + expf(-z[0]));
    float fv = 1.0f / (1.0f + expf(-z[1]));
    float ov = 1.0f / (1.0f + expf(-z[2]));
    float gv = tanhf(z[3]);
    int U = q * 16 + u;
    size_t sidx = ((size_t)b * HH + rr) * HID + U;
    float cv = c_state[sidx];
    float cn = fv * cv + iv * gv;
    c_state[sidx] = cn;
    float hn = ov * tanhf(cn);
    h_next[sidx] = hn;
    int wcol = t - rr;
    if (wcol >= 0 && wcol < WW) {
      out[(((size_t)b * HID + U) * HH + rr) * WW + wcol] = hn;
    }
  }
}

extern "C" void kernel_launch(void* const* d_in, const int* in_sizes, int n_in,
                              void* d_out, int out_size, void* d_ws,
                              size_t ws_size, hipStream_t stream) {
  const float* x = (const float*)d_in[0];
  const float* w_is = (const float*)d_in[1];
  const float* b_is = (const float*)d_in[2];
  const float* w_ss = (const float*)d_in[3];
  const float* b_ss = (const float*)d_in[4];
  float* outp = (float*)d_out;

  const size_t zph_bytes = (size_t)BB * HH * WW * 512 * 2;  // 32 MiB
  const size_t wp_bytes = (size_t)512 * 256 * 2;            // 256 KiB
  const size_t wisa_bytes = (size_t)512 * 128 * 2;          // 128 KiB
  const size_t hx_bytes = (size_t)TT * 8 * 4 * 64 * 8;      // ~2.03 MiB
  const size_t need = zph_bytes + wp_bytes + wisa_bytes + hx_bytes;

  char* ws = (char*)d_ws;
  if (ws_size >= need) {
    __half* zph = (__half*)ws;
    _Float16* wpp = (_Float16*)(ws + zph_bytes);
    _Float16* wisa = (_Float16*)(ws + zph_bytes + wp_bytes);
    unsigned long long* hx =
        (unsigned long long*)(ws + zph_bytes + wp_bytes + wisa_bytes);

    // prep_all: 131072 + 65536 + 260096 + 2097152 = 2,553,856 -> 9976 blocks
    prep_all<<<dim3(9976), 256, 0, stream>>>(w_ss, w_is, wpp, wisa, hx, zph);
    lstm_fused<<<dim3(288), 512, 0, stream>>>(x, wisa, zph, wpp, b_is, b_ss,
                                              hx, outp);
  } else {
    // -------- round-1 fallback --------
    const size_t xT_elems = (size_t)BB * HH * WW * 128;
    const size_t st_elems = (size_t)BB * HH * HID;
    const size_t need_xT = (xT_elems + 3 * st_elems) * sizeof(float);
    float* wsf = (float*)d_ws;
    float* xT = nullptr;
    float* st;
    int use_xT = 0;
    if (ws_size >= need_xT) {
      use_xT = 1;
      xT = wsf;
      st = wsf + xT_elems;
    } else {
      st = wsf;
    }
    float* h0 = st;
    float* h1 = st + st_elems;
    float* cb = st + 2 * st_elems;
    hipMemsetAsync(st, 0, 3 * st_elems * sizeof(float), stream);
    if (use_xT) transpose_x<<<dim3(BB * HH), 256, 0, stream>>>(x, xT);
    for (int t = 0; t < TT; t++) {
      float* hp = (t & 1) ? h1 : h0;
      float* hn = (t & 1) ? h0 : h1;
      step_kernel<<<dim3(32, 8), 256, 0, stream>>>(x, xT, use_xT, w_is, b_is,
                                                   w_ss, b_ss, hp, hn, cb, outp,
                                                   t);
    }
  }
}

// Round 12
// 349.836 us; speedup vs baseline: 1.3307x; 1.3307x over previous
//
#include <hip/hip_runtime.h>
#include <hip/hip_fp16.h>
#include <math.h>

// DiagonalLSTM: B=8, Cin=HID=128, H=64, W=64, K=2, T = 2W-1 = 127 steps.
//
// Round 12 design (revert to round-10 structure + prologue trims):
//   - lstm_mfma EXACTLY as round 10 (best measured: 250 us steady):
//     sentinel hx exchange (fire-and-forget 8B stores, data==flag, zero
//     drains), 1 barrier/step, boundary+zp prefetched 1 step ahead,
//     contiguous zph layout, reg-buffered out stores, MFMA via intrinsics.
//   - hx sentinel = 0xFF bytes via hipMemsetAsync (f16 0xFFFF = -NaN,
//     unreachable from packing clamped-finite h) -> SENT64 = ~0ULL; the
//     1016-block sentinel fill leaves prep entirely.
//   - prep_w2: weight fragments only (768 blocks).
//   - zpre_mfma: x-staging re-mapped for coalescing (16-lane groups read one
//     contiguous 256B c-row; was 16KB-strided per lane -> 4x overfetch).
//   - Round-11 fusion REVERTED: sharing zph producer/consumer in one kernel
//     forces uncached zph traffic (WRITE_SIZE 18->149MB, lstm 250->393us).

#define HID 128
#define BB 8
#define HH 64
#define WW 64
#define TT 127

typedef _Float16 v8h __attribute__((ext_vector_type(8)));
typedef float v4f __attribute__((ext_vector_type(4)));

#define SENT64 0xFFFFFFFFFFFFFFFFULL  // 4x f16 -NaN (memset 0xFF pattern)

__device__ __forceinline__ float fsig(float x) {
  x = __builtin_fmaxf(__builtin_fminf(x, 30.f), -30.f);
  float e = __builtin_amdgcn_exp2f(x * -1.44269504f);
  return __builtin_amdgcn_rcpf(1.f + e);
}
__device__ __forceinline__ float ftanh_(float x) {
  x = __builtin_fmaxf(__builtin_fminf(x, 15.f), -15.f);
  float e = __builtin_amdgcn_exp2f(x * 2.88539009f);
  return (e - 1.f) * __builtin_amdgcn_rcpf(e + 1.f);
}

// ---- prep_w2: w_ss frags (131072) + w_is frags (65536) ----
__global__ __launch_bounds__(256) void prep_w2(const float* __restrict__ w_ss,
                                               const float* __restrict__ w_is,
                                               _Float16* __restrict__ wp,
                                               _Float16* __restrict__ wisa) {
  int idx = blockIdx.x * 256 + threadIdx.x;
  if (idx < 131072) {
    // w_ss -> Wcat(512x256) A-frags: wp[(((mt*8+kt)*64+L)*8+j)]
    int j = idx & 7;
    int L = (idx >> 3) & 63;
    int kt = (idx >> 9) & 7;
    int mt = idx >> 12;  // 0..31
    int O = mt * 16 + (L & 15);
    int k = kt * 32 + ((L >> 4) & 3) * 8 + j;
    float v = (k < 128) ? w_ss[(size_t)O * 256 + k * 2]
                        : w_ss[(size_t)O * 256 + (k - 128) * 2 + 1];
    wp[idx] = (_Float16)v;
  } else if (idx < 196608) {
    // w_is (512x128) A-frags: wisa[(((mt*4+kt)*64+L)*8+j)]
    int i2 = idx - 131072;
    int j = i2 & 7;
    int L = (i2 >> 3) & 63;
    int kt = (i2 >> 9) & 3;
    int mt = i2 >> 11;  // 0..31
    int O = mt * 16 + (L & 15);
    int k = kt * 32 + ((L >> 4) & 3) * 8 + j;
    wisa[i2] = (_Float16)w_is[(size_t)O * 128 + k];
  }
}

// ---- zpre_mfma: zph[pos*512 + (u>>2)*16 + g*4 + (u&3)] ----
__global__ __launch_bounds__(256) void zpre_mfma(const float* __restrict__ x,
                                                 const _Float16* __restrict__ wisa,
                                                 __half* __restrict__ zph) {
  const int b = blockIdx.x >> 6;
  const int r = blockIdx.x & 63;
  const int tid = threadIdx.x;
  const int wv = tid >> 6;  // 0..3 -> ntile
  const int L = tid & 63;
  const int quad = L >> 4;
  const int l15 = L & 15;

  __shared__ _Float16 xt[64][136];  // [w][c] f16, padded

  // stage x(b,:,r,:) -> xt transposed; 16-lane groups read one contiguous
  // 256B c-row (coalesced; old map read 16KB-strided rows -> 4x overfetch)
  {
    const int cw = tid >> 4;        // c within pass
    const int w4 = (tid & 15) * 4;  // w base
#pragma unroll
    for (int p = 0; p < 8; p++) {
      int c = p * 16 + cw;
      float4 v = *(const float4*)&x[(((size_t)b * 128 + c) * HH + r) * WW + w4];
      xt[w4 + 0][c] = (_Float16)v.x;
      xt[w4 + 1][c] = (_Float16)v.y;
      xt[w4 + 2][c] = (_Float16)v.z;
      xt[w4 + 3][c] = (_Float16)v.w;
    }
  }
  __syncthreads();

  const int wcol = wv * 16 + l15;  // B-side n
  v8h bf[4];
#pragma unroll
  for (int kt = 0; kt < 4; kt++)
    bf[kt] = *(const v8h*)&xt[wcol][kt * 32 + quad * 8];

  const size_t pos = ((size_t)b * HH + r) * WW + wcol;
  const v8h* wa8 = (const v8h*)wisa;

#pragma unroll 4
  for (int mt = 0; mt < 32; mt++) {
    v4f acc = (v4f){0.f, 0.f, 0.f, 0.f};
#pragma unroll
    for (int kt = 0; kt < 4; kt++) {
      v8h af = wa8[((size_t)mt * 4 + kt) * 64 + L];
      acc = __builtin_amdgcn_mfma_f32_16x16x32_f16(af, bf[kt], acc, 0, 0, 0);
    }
    // u = (mt&7)*16+quad*4+reg, g = mt>>3
    // store idx = ((u>>2)*16 + g*4 + (u&3)) = ((mt&7)*4+quad)*16 + g*4 + reg
    __half2 lo = __floats2half2_rn(acc[0], acc[1]);
    __half2 hi = __floats2half2_rn(acc[2], acc[3]);
    uint2 pk;
    pk.x = *(unsigned*)&lo;
    pk.y = *(unsigned*)&hi;
    *(uint2*)&zph[pos * 512 + ((mt & 7) * 4 + quad) * 16 + (mt >> 3) * 4] = pk;
  }
}

// ---------------- persistent MFMA recurrent kernel (round-10) -------------
#define HROW 136  // padded row stride in halfs

__global__ __launch_bounds__(512, 1) void lstm_mfma(
    const __half* __restrict__ zph, const _Float16* __restrict__ wp,
    const float* __restrict__ b_is, const float* __restrict__ b_ss,
    unsigned long long* __restrict__ hx,  // [TT][8][4][64], sentinel-filled
    float* __restrict__ out) {
  const int blk = blockIdx.x;  // 0..31
  const int rgr = blk >> 2;    // row group 0..7 (rows 8*rgr .. +7)
  const int bg = blk & 3;      // batch group 0..3 (b = 2*bg, 2*bg+1)
  const int R0 = rgr * 8;
  const int tid = threadIdx.x;
  const int wv = tid >> 6;  // wave 0..7
  const int L = tid & 63;
  const int quad = L >> 4;
  const int l15 = L & 15;
  const int rl = l15 >> 1;  // cell row-local 0..7
  const int bl = l15 & 1;   // cell batch-local 0..1
  const int b = bg * 2 + bl;
  const int r = R0 + rl;
  const int uq0 = 16 * wv + quad * 4;     // D-side unit base (+reg)
  const int zoff = (4 * wv + quad) * 16;  // zp contiguous 16-half group

  // double-buffered: slot s holds row R0-1+s (s=0..8), per b-local
  __shared__ _Float16 h_lds[2][9 * 2 * HROW];
  for (int i = tid; i < (2 * 9 * 2 * HROW) / 2; i += 512)
    ((unsigned*)h_lds)[i] = 0u;

  // ---- weights as A-fragments, loaded once ----
  v8h wfrag[4][8];
  {
    const v8h* wp8 = (const v8h*)wp;
#pragma unroll
    for (int g = 0; g < 4; g++)
#pragma unroll
      for (int kt = 0; kt < 8; kt++)
        wfrag[g][kt] = wp8[((size_t)((8 * g + wv) * 8 + kt)) * 64 + L];
  }

  float bsum[4][4];
#pragma unroll
  for (int g = 0; g < 4; g++)
#pragma unroll
    for (int rg2 = 0; rg2 < 4; rg2++) {
      int O = g * 128 + uq0 + rg2;
      bsum[g][rg2] = b_is[O] + b_ss[O];
    }

  float c[4] = {0.f, 0.f, 0.f, 0.f};
  float4 outb[4];  // shift-window out buffer (w-3..w per cell)
#pragma unroll
  for (int i = 0; i < 4; i++) outb[i] = make_float4(0.f, 0.f, 0.f, 0.f);

  const int ebl = L >> 5;       // boundary consumer: b-local
  const int eu = (L & 31) * 4;  // boundary consumer: unit base
  const int exp_idx = bl * 32 + 4 * wv + quad;  // producer slot (l15>=14)

  const bool is_cons = (wv == 0) && (rgr > 0);

  // ---- zp for t=0 (contiguous 32B: h[g*4+rg2]) ----
  union ZU {
    uint4 q[2];
    __half h[16];
  } zu;
  zu.q[0] = (uint4){0u, 0u, 0u, 0u};
  zu.q[1] = (uint4){0u, 0u, 0u, 0u};
  if (r == 0) {
    const uint4* p = (const uint4*)(zph + ((size_t)b * HH * WW) * 512 + zoff);
    zu.q[0] = p[0];
    zu.q[1] = p[1];
  }

  // ---- boundary pipeline: pend = load of hx[t] (validated at end of t) ----
  unsigned long long pend = 0ull;
  if (is_cons) {
    pend = __hip_atomic_load(&hx[(((size_t)0 * 8 + (rgr - 1)) * 4 + bg) * 64 + L],
                             __ATOMIC_RELAXED, __HIP_MEMORY_SCOPE_AGENT);
  }

  __syncthreads();

  for (int t = 0; t < TT; t++) {
    const int rb = t & 1;
    const int wb = rb ^ 1;

    // ---- issue next boundary load (hx[t+1], consumed end of t+1) ----
    unsigned long long newp = 0ull;
    if (is_cons && (t + 1) < TT) {
      newp = __hip_atomic_load(
          &hx[(((size_t)(t + 1) * 8 + (rgr - 1)) * 4 + bg) * 64 + L],
          __ATOMIC_RELAXED, __HIP_MEMORY_SCOPE_AGENT);
    }

    // ---- MFMA: kt 0..3 -> rows r-1 (slot rl); kt 4..7 -> rows r (slot rl+1)
    v4f acc[4];
#pragma unroll
    for (int g = 0; g < 4; g++) acc[g] = (v4f){0.f, 0.f, 0.f, 0.f};
#pragma unroll
    for (int kt = 0; kt < 8; kt++) {
      const int slot = (kt < 4) ? rl : (rl + 1);
      v8h bf = *(const v8h*)&h_lds[rb][(slot * 2 + bl) * HROW +
                                       (kt & 3) * 32 + quad * 8];
#pragma unroll
      for (int g = 0; g < 4; g++)
        acc[g] = __builtin_amdgcn_mfma_f32_16x16x32_f16(wfrag[g][kt], bf,
                                                        acc[g], 0, 0, 0);
    }

    // ---- gates ----
    const int w = t - r;
    const bool inband = (w >= 0) && (w < WW);
    float hv[4];
#pragma unroll
    for (int rg2 = 0; rg2 < 4; rg2++) {
      float z0 = acc[0][rg2] + bsum[0][rg2] + __half2float(zu.h[0 * 4 + rg2]);
      float z1 = acc[1][rg2] + bsum[1][rg2] + __half2float(zu.h[1 * 4 + rg2]);
      float z2 = acc[2][rg2] + bsum[2][rg2] + __half2float(zu.h[2 * 4 + rg2]);
      float z3 = acc[3][rg2] + bsum[3][rg2] + __half2float(zu.h[3 * 4 + rg2]);
      float iv = fsig(z0);
      float fv = fsig(z1);
      float ov = fsig(z2);
      float gv = ftanh_(z3);
      c[rg2] = fv * c[rg2] + iv * gv;
      hv[rg2] = ov * ftanh_(c[rg2]);
    }

    // ---- h(t) -> wb slots 1..8 (LDS, 8B per lane) ----
    {
      __half2 lo = __floats2half2_rn(hv[0], hv[1]);
      __half2 hi = __floats2half2_rn(hv[2], hv[3]);
      uint2 pk;
      pk.x = *(unsigned*)&lo;
      pk.y = *(unsigned*)&hi;
      *(uint2*)&h_lds[wb][((rl + 1) * 2 + bl) * HROW + uq0] = pk;
    }

    // ---- export h(t)[R0+7]: fire-and-forget (data == flag, no drain) ----
    if (rgr < 7 && l15 >= 14) {
      __half2 lo = __floats2half2_rn(hv[0], hv[1]);
      __half2 hi = __floats2half2_rn(hv[2], hv[3]);
      unsigned long long pk =
          ((unsigned long long)*(unsigned*)&hi << 32) | *(unsigned*)&lo;
      __hip_atomic_store(&hx[(((size_t)t * 8 + rgr) * 4 + bg) * 64 + exp_idx],
                         pk, __ATOMIC_RELAXED, __HIP_MEMORY_SCOPE_AGENT);
    }

    // ---- out shift-window; coalesced 16B flush every 4 steps per cell ----
#pragma unroll
    for (int rg2 = 0; rg2 < 4; rg2++) {
      outb[rg2].x = outb[rg2].y;
      outb[rg2].y = outb[rg2].z;
      outb[rg2].z = outb[rg2].w;
      outb[rg2].w = hv[rg2];
    }
    if (inband && (w & 3) == 3) {
      float* op_ = out + (((size_t)b * HID + uq0) * HH + r) * WW + (w - 3);
#pragma unroll
      for (int rg2 = 0; rg2 < 4; rg2++) {
        *(float4*)(op_ + (size_t)rg2 * (HH * WW)) = outb[rg2];
      }
    }

    // ---- zp prefetch for t+1 (contiguous 32B) ----
    {
      const int wn = t + 1 - r;
      if (wn >= 0 && wn < WW) {
        const uint4* p =
            (const uint4*)(zph + (((size_t)b * HH + r) * WW + wn) * 512 + zoff);
        zu.q[0] = p[0];
        zu.q[1] = p[1];
      } else {
        zu.q[0] = (uint4){0u, 0u, 0u, 0u};
        zu.q[1] = (uint4){0u, 0u, 0u, 0u};
      }
    }

    // ---- validate pend (hx[t] = h(t)[R0-1]), write to wb slot 0 ----
    if (is_cons) {
      const unsigned long long* addr =
          &hx[(((size_t)t * 8 + (rgr - 1)) * 4 + bg) * 64 + L];
      while (__ballot(pend == SENT64) != 0ull) {
        __builtin_amdgcn_s_sleep(1);
        pend = __hip_atomic_load(addr, __ATOMIC_RELAXED,
                                 __HIP_MEMORY_SCOPE_AGENT);
      }
      *(unsigned long long*)&h_lds[wb][(0 * 2 + ebl) * HROW + eu] = pend;
      pend = newp;
    }

    __syncthreads();  // wb complete; rb free for rewrite next step
  }
}

// ================= round-1 fallback path (proven correct) =================
__global__ __launch_bounds__(256) void transpose_x(const float* __restrict__ x,
                                                   float* __restrict__ xT) {
  int b = blockIdx.x >> 6;
  int r = blockIdx.x & 63;
  __shared__ float tile[32][65];
  for (int cc = 0; cc < 4; cc++) {
    int cl = threadIdx.x >> 6;
    int w = threadIdx.x & 63;
#pragma unroll
    for (int k = 0; k < 8; k++) {
      int c_loc = k * 4 + cl;
      int c = cc * 32 + c_loc;
      tile[c_loc][w] = x[(((size_t)b * 128 + c) * HH + r) * WW + w];
    }
    __syncthreads();
    int cs = threadIdx.x & 31;
    int wp = threadIdx.x >> 5;
#pragma unroll
    for (int k = 0; k < 8; k++) {
      int w2 = wp * 8 + k;
      xT[(((size_t)b * HH + r) * WW + w2) * 128 + cc * 32 + cs] = tile[cs][w2];
    }
    __syncthreads();
  }
}

__global__ __launch_bounds__(256) void step_kernel(
    const float* __restrict__ x, const float* __restrict__ xT, int use_xT,
    const float* __restrict__ w_is, const float* __restrict__ b_is,
    const float* __restrict__ w_ss, const float* __restrict__ b_ss,
    const float* __restrict__ h_prev, float* __restrict__ h_next,
    float* __restrict__ c_state, float* __restrict__ out, int t) {
  const int rg = blockIdx.x;
  const int q = blockIdx.y;
  const int r0 = rg * 2;
  const int tid = threadIdx.x;
  const int o_loc = tid & 63;
  const int k4 = tid >> 6;
  const int g_ = o_loc >> 4;
  const int u_ = o_loc & 15;
  const int O = g_ * 128 + q * 16 + u_;
  const int i0 = k4 * 32;

  __shared__ __align__(16) float h_in[3][BB][HID];
  __shared__ float zred[16][4][65];

  for (int idx = tid; idx < 3 * BB * HID; idx += 256) {
    int row_sel = idx >> 10;
    int rem = idx & 1023;
    int b = rem >> 7;
    int u = rem & 127;
    int rr = r0 - 1 + row_sel;
    h_in[row_sel][b][u] = (rr >= 0) ? h_prev[((size_t)b * HH + rr) * HID + u] : 0.0f;
  }

  float wr0[32], wr1[32], wz[32];
  {
    const float4* wss4 = (const float4*)(w_ss + ((size_t)O * 128 + i0) * 2);
#pragma unroll
    for (int j = 0; j < 16; j++) {
      float4 v = wss4[j];
      wr0[2 * j] = v.x;
      wr1[2 * j] = v.y;
      wr0[2 * j + 1] = v.z;
      wr1[2 * j + 1] = v.w;
    }
    const float4* wis4 = (const float4*)(w_is + (size_t)O * 128 + i0);
#pragma unroll
    for (int j = 0; j < 8; j++) {
      float4 v = wis4[j];
      wz[4 * j] = v.x;
      wz[4 * j + 1] = v.y;
      wz[4 * j + 2] = v.z;
      wz[4 * j + 3] = v.w;
    }
  }

  __syncthreads();

  float acc[2][BB];
#pragma unroll
  for (int rl = 0; rl < 2; rl++)
#pragma unroll
    for (int b = 0; b < BB; b++) acc[rl][b] = 0.0f;

#pragma unroll
  for (int jb = 0; jb < 8; jb++) {
    int ib = i0 + jb * 4;
#pragma unroll
    for (int b = 0; b < BB; b++) {
      const float4 hm4 = *(const float4*)&h_in[0][b][ib];
      const float4 hc4 = *(const float4*)&h_in[1][b][ib];
      const float4 hp4 = *(const float4*)&h_in[2][b][ib];
      const float* hm = (const float*)&hm4;
      const float* hc = (const float*)&hc4;
      const float* hq = (const float*)&hp4;
#pragma unroll
      for (int jj = 0; jj < 4; jj++) {
        float w0v = wr0[jb * 4 + jj];
        float w1v = wr1[jb * 4 + jj];
        acc[0][b] += w0v * hm[jj] + w1v * hc[jj];
        acc[1][b] += w0v * hc[jj] + w1v * hq[jj];
      }
    }
  }

#pragma unroll
  for (int rl = 0; rl < 2; rl++) {
    int rr = r0 + rl;
    int wcol = t - rr;
    if (wcol >= 0 && wcol < WW) {
      if (use_xT) {
        for (int b = 0; b < BB; b++) {
          const float4* xp =
              (const float4*)(xT + (((size_t)b * HH + rr) * WW + wcol) * 128 + i0);
#pragma unroll
          for (int j = 0; j < 8; j++) {
            float4 v = xp[j];
            acc[rl][b] += wz[4 * j] * v.x + wz[4 * j + 1] * v.y +
                          wz[4 * j + 2] * v.z + wz[4 * j + 3] * v.w;
          }
        }
      } else {
        for (int b = 0; b < BB; b++) {
          const float* xb = x + (((size_t)b * 128 + i0) * HH + rr) * WW + wcol;
#pragma unroll
          for (int j = 0; j < 32; j++) {
            acc[rl][b] += wz[j] * xb[(size_t)j * HH * WW];
          }
        }
      }
    }
  }

#pragma unroll
  for (int rl = 0; rl < 2; rl++)
#pragma unroll
    for (int b = 0; b < BB; b++) zred[rl * 8 + b][k4][o_loc] = acc[rl][b];
  __syncthreads();

  {
    int u = tid >> 4;
    int cell = tid & 15;
    int rl = cell >> 3;
    int b = cell & 7;
    int rr = r0 + rl;
    float z[4];
#pragma unroll
    for (int gg = 0; gg < 4; gg++) {
      int ol = gg * 16 + u;
      float s = zred[cell][0][ol] + zred[cell][1][ol] + zred[cell][2][ol] +
                zred[cell][3][ol];
      int Og = gg * 128 + q * 16 + u;
      z[gg] = s + b_is[Og] + b_ss[Og];
    }
    float iv = 1.0f / (1.0f + expf(-z[0]));
    float fv = 1.0f / (1.0f + expf(-z[1]));
    float ov = 1.0f / (1.0f + expf(-z[2]));
    float gv = tanhf(z[3]);
    int U = q * 16 + u;
    size_t sidx = ((size_t)b * HH + rr) * HID + U;
    float cv = c_state[sidx];
    float cn = fv * cv + iv * gv;
    c_state[sidx] = cn;
    float hn = ov * tanhf(cn);
    h_next[sidx] = hn;
    int wcol = t - rr;
    if (wcol >= 0 && wcol < WW) {
      out[(((size_t)b * HID + U) * HH + rr) * WW + wcol] = hn;
    }
  }
}

extern "C" void kernel_launch(void* const* d_in, const int* in_sizes, int n_in,
                              void* d_out, int out_size, void* d_ws,
                              size_t ws_size, hipStream_t stream) {
  const float* x = (const float*)d_in[0];
  const float* w_is = (const float*)d_in[1];
  const float* b_is = (const float*)d_in[2];
  const float* w_ss = (const float*)d_in[3];
  const float* b_ss = (const float*)d_in[4];
  float* outp = (float*)d_out;

  const size_t zph_bytes = (size_t)BB * HH * WW * 512 * 2;  // 32 MiB
  const size_t wp_bytes = (size_t)512 * 256 * 2;            // 256 KiB
  const size_t wisa_bytes = (size_t)512 * 128 * 2;          // 128 KiB
  const size_t hx_bytes = (size_t)TT * 8 * 4 * 64 * 8;      // ~2.03 MiB
  const size_t need = zph_bytes + wp_bytes + wisa_bytes + hx_bytes;

  char* ws = (char*)d_ws;
  if (ws_size >= need) {
    __half* zph = (__half*)ws;
    _Float16* wpp = (_Float16*)(ws + zph_bytes);
    _Float16* wisa = (_Float16*)(ws + zph_bytes + wp_bytes);
    unsigned long long* hx =
        (unsigned long long*)(ws + zph_bytes + wp_bytes + wisa_bytes);

    hipMemsetAsync(hx, 0xFF, hx_bytes, stream);  // sentinel = all-ones (-NaN)
    prep_w2<<<dim3(768), 256, 0, stream>>>(w_ss, w_is, wpp, wisa);
    zpre_mfma<<<dim3(BB * HH), 256, 0, stream>>>(x, wisa, zph);
    lstm_mfma<<<dim3(32), 512, 0, stream>>>(zph, wpp, b_is, b_ss, hx, outp);
  } else {
    // -------- round-1 fallback --------
    const size_t xT_elems = (size_t)BB * HH * WW * 128;
    const size_t st_elems = (size_t)BB * HH * HID;
    const size_t need_xT = (xT_elems + 3 * st_elems) * sizeof(float);
    float* wsf = (float*)d_ws;
    float* xT = nullptr;
    float* st;
    int use_xT = 0;
    if (ws_size >= need_xT) {
      use_xT = 1;
      xT = wsf;
      st = wsf + xT_elems;
    } else {
      st = wsf;
    }
    float* h0 = st;
    float* h1 = st + st_elems;
    float* cb = st + 2 * st_elems;
    hipMemsetAsync(st, 0, 3 * st_elems * sizeof(float), stream);
    if (use_xT) transpose_x<<<dim3(BB * HH), 256, 0, stream>>>(x, xT);
    for (int t = 0; t < TT; t++) {
      float* hp = (t & 1) ? h1 : h0;
      float* hn = (t & 1) ? h0 : h1;
      step_kernel<<<dim3(32, 8), 256, 0, stream>>>(x, xT, use_xT, w_is, b_is,
                                                   w_ss, b_ss, hp, hn, cb, outp,
                                                   t);
    }
  }
}